// Round 12
// baseline (1997.143 us; speedup 1.0000x reference)
//
#include <hip/hip_runtime.h>

#define D_ 128
#define BATCH_ 65536
#define BSH 10          // bucket = 1024 destinations
#define TILE_ 16384     // edges per scatter block

typedef _Float16 f16;
typedef _Float16 h2v __attribute__((ext_vector_type(2)));
typedef _Float16 f16x8 __attribute__((ext_vector_type(8)));
typedef float f32x4 __attribute__((ext_vector_type(4)));

// ---------------- utility ----------------
__global__ void k_zero32(uint32_t* p, long long n) {
    long long i = (long long)blockIdx.x * blockDim.x + threadIdx.x;
    long long st = (long long)gridDim.x * blockDim.x;
    for (; i < n; i += st) p[i] = 0u;
}

__global__ void k_sentinel(float* p, long long n) {
    long long i = (long long)blockIdx.x * blockDim.x + threadIdx.x;
    long long st = (long long)gridDim.x * blockDim.x;
    for (; i < n; i += st) p[i] = -12345.0f;
}

// transpose+convert 128x128 weight: Wt[c][k] = (f16)W[k][c]
__global__ void k_wt(const float* __restrict__ W, f16* __restrict__ Wt) {
    int t = blockIdx.x * 256 + threadIdx.x;
    int k = t >> 7, c = t & 127;
    Wt[c * 128 + k] = (f16)W[k * 128 + c];
}

// row gather: dst[i][:] = src[perm[i]][:]   (fp16 rows as u32 pairs)
__global__ void k_gath(const uint32_t* __restrict__ src, const int* __restrict__ perm,
                       uint32_t* __restrict__ dst, int N) {
    int i = blockIdx.x * 256 + threadIdx.x;
    if (i >= N * 64) return;
    int row = i >> 6, col = i & 63;
    dst[i] = src[((size_t)perm[row] << 6) + col];
}

// ---------------- bucketed CSR build ----------------
__global__ void k_hist(const int* __restrict__ ei, int* __restrict__ bcnt,
                       int E, int nbt, int nbuk) {
    __shared__ int hist[512];
    for (int i = threadIdx.x; i < 512; i += 256) hist[i] = 0;
    __syncthreads();
    long long tot = 3LL * E;
    long long i = (long long)blockIdx.x * 256 + threadIdx.x;
    long long st = (long long)gridDim.x * 256;
    for (; i < tot; i += st) {
        int t = (i >= E) + (i >= 2LL * E);
        long long w = i - (long long)t * E;
        int dst = ei[(long long)t * 2 * E + E + w];
        atomicAdd(&hist[t * nbt + (dst >> BSH)], 1);
    }
    __syncthreads();
    for (int i2 = threadIdx.x; i2 < nbuk; i2 += 256)
        if (hist[i2]) atomicAdd(&bcnt[i2], hist[i2]);
}

__global__ void k_bscan(const int* __restrict__ bcnt, int* __restrict__ bbase,
                        int* __restrict__ bcur, int nbuk) {
    __shared__ int s[512];
    int t = threadIdx.x;
    int v = (t < nbuk) ? bcnt[t] : 0;
    s[t] = v;
    __syncthreads();
    for (int off = 1; off < 512; off <<= 1) {
        int a = (t >= off) ? s[t - off] : 0;
        __syncthreads();
        s[t] += a;
        __syncthreads();
    }
    if (t < nbuk) {
        int e = s[t] - v;
        bbase[t] = e;
        bcur[t] = e;
        if (t == nbuk - 1) bbase[nbuk] = s[t];
    }
}

__global__ __launch_bounds__(256) void k_scatter(const int* __restrict__ ei,
                                                 int* __restrict__ bcur,
                                                 uint32_t* __restrict__ pairs,
                                                 int E, int nbt, int nbuk) {
    __shared__ int hist[512];
    __shared__ int base[512];
    long long tot = 3LL * E;
    long long w0 = (long long)blockIdx.x * TILE_;
    long long w1 = w0 + TILE_ < tot ? w0 + TILE_ : tot;
    for (int i = threadIdx.x; i < 512; i += 256) hist[i] = 0;
    __syncthreads();
    for (long long e = w0 + threadIdx.x; e < w1; e += 256) {
        int t = (e >= E) + (e >= 2LL * E);
        long long w = e - (long long)t * E;
        int dst = ei[(long long)t * 2 * E + E + w];
        atomicAdd(&hist[t * nbt + (dst >> BSH)], 1);
    }
    __syncthreads();
    for (int i = threadIdx.x; i < nbuk; i += 256) {
        int c = hist[i];
        base[i] = c ? atomicAdd(&bcur[i], c) : 0;
        hist[i] = 0;
    }
    __syncthreads();
    for (long long e = w0 + threadIdx.x; e < w1; e += 256) {
        int t = (e >= E) + (e >= 2LL * E);
        long long w = e - (long long)t * E;
        int src = ei[(long long)t * 2 * E + w];
        int dst = ei[(long long)t * 2 * E + E + w];
        int b = t * nbt + (dst >> BSH);
        int off = atomicAdd(&hist[b], 1);
        pairs[base[b] + off] = (uint32_t)src | ((uint32_t)(dst & ((1 << BSH) - 1)) << 22);
    }
}

__global__ __launch_bounds__(256) void k_bucket(const uint32_t* __restrict__ pairs,
                                                const int* __restrict__ bbase,
                                                int* __restrict__ rowstart,
                                                float* __restrict__ dinv,
                                                int* __restrict__ csr,
                                                int N, int nbt, int nbuk, int L) {
    __shared__ int cnt[1024];
    __shared__ int pref[1024];
    __shared__ int sums[256];
    int b = blockIdx.x;
    int t = b / nbt, bb = b - t * nbt;
    int dst0 = bb << BSH;
    int ndst = (N - dst0 < 1024) ? (N - dst0) : 1024;
    int e0 = bbase[b], e1 = bbase[b + 1];
    int tid = threadIdx.x;
    for (int i = tid; i < 1024; i += 256) cnt[i] = 0;
    __syncthreads();
    for (int e = e0 + tid; e < e1; e += 256) atomicAdd(&cnt[pairs[e] >> 22], 1);
    __syncthreads();
    int i0 = tid * 4;
    int c0 = cnt[i0], c1 = cnt[i0 + 1], c2 = cnt[i0 + 2], c3 = cnt[i0 + 3];
    int s4 = c0 + c1 + c2 + c3;
    sums[tid] = s4;
    __syncthreads();
    for (int off = 1; off < 256; off <<= 1) {
        int v = (tid >= off) ? sums[tid - off] : 0;
        __syncthreads();
        sums[tid] += v;
        __syncthreads();
    }
    int run = sums[tid] - s4;
    pref[i0] = run; run += c0;
    pref[i0 + 1] = run; run += c1;
    pref[i0 + 2] = run; run += c2;
    pref[i0 + 3] = run;
    __syncthreads();
    for (int d = tid; d < ndst; d += 256) {
        int r = t * N + dst0 + d;
        rowstart[r] = e0 + pref[d];
        dinv[r] = rsqrtf((float)cnt[d] + 1.0f);
    }
    if (b == nbuk - 1 && tid == 0) rowstart[L] = e1;
    __syncthreads();
    for (int e = e0 + tid; e < e1; e += 256) {
        uint32_t u = pairs[e];
        int d = u >> 22;
        int pos = e0 + atomicAdd(&pref[d], 1);
        csr[pos] = (int)(u & ((1u << 22) - 1));
    }
}

// ---------------- degree sort: ord = rows sorted by (type, degree) ----------------
__global__ void k_dhist(const int* __restrict__ rowstart, int* __restrict__ dh,
                        int N, int L) {
    int r = blockIdx.x * 256 + threadIdx.x;
    if (r >= L) return;
    int deg = rowstart[r + 1] - rowstart[r];
    if (deg > 255) deg = 255;
    int t = (r >= N) + (r >= 2 * N);
    atomicAdd(&dh[t * 256 + deg], 1);
}

__global__ void k_dscan(const int* __restrict__ dh, int* __restrict__ dcur, int nb) {
    __shared__ int s[1024];
    int t = threadIdx.x;
    int v = (t < nb) ? dh[t] : 0;
    s[t] = v;
    __syncthreads();
    for (int off = 1; off < 1024; off <<= 1) {
        int a = (t >= off) ? s[t - off] : 0;
        __syncthreads();
        s[t] += a;
        __syncthreads();
    }
    if (t < nb) dcur[t] = s[t] - v;
}

__global__ void k_dorder(const int* __restrict__ rowstart, int* __restrict__ dcur,
                         int* __restrict__ ord, int N, int L) {
    int r = blockIdx.x * 256 + threadIdx.x;
    if (r >= L) return;
    int deg = rowstart[r + 1] - rowstart[r];
    if (deg > 255) deg = 255;
    int t = (r >= N) + (r >= 2 * N);
    int pos = atomicAdd(&dcur[t * 256 + deg], 1);
    ord[pos] = r;
}

// CSR-aligned edge weights: w16[e] = (f16)dinv_t[src_e]  (valid for BOTH layers)
__global__ void k_wedge(const int* __restrict__ csr, const float* __restrict__ dinv,
                        f16* __restrict__ w16, int N, int E) {
    long long tot = 3LL * E;
    long long i = (long long)blockIdx.x * 256 + threadIdx.x;
    long long st = (long long)gridDim.x * 256;
    for (; i < tot; i += st) {
        int t = (i >= E) + (i >= 2LL * E);
        w16[i] = (f16)dinv[t * N + csr[i]];
    }
}

// ---------------- MFMA GEMM: out(f16) = [relu](in @ W [+ bias]); 32 rows/wave ----------------
__global__ __launch_bounds__(256) void k_mgemm(const void* __restrict__ in, int in_f32,
                                               const f16* __restrict__ Wt,
                                               const float* __restrict__ bias,
                                               f16* __restrict__ outh, int n, int relu) {
    int l = threadIdx.x & 63, wid = threadIdx.x >> 6;
    int row0 = blockIdx.x * 128 + wid * 32;
    int r = l & 15, kg = l >> 4;
    f32x4 acc[2][8] = {};
#pragma unroll
    for (int kk = 0; kk < 4; kk++) {
        int off = kk * 32 + kg * 8;
        f16x8 a[2];
#pragma unroll
        for (int h = 0; h < 2; h++) {
            int arow = row0 + h * 16 + r;
            f16x8 av = {};
            if (arow < n) {
                if (in_f32) {
                    const float* inf = (const float*)in + (size_t)arow * D_ + off;
                    float4 v0 = *(const float4*)inf;
                    float4 v1 = *(const float4*)(inf + 4);
                    av[0] = (f16)v0.x; av[1] = (f16)v0.y; av[2] = (f16)v0.z; av[3] = (f16)v0.w;
                    av[4] = (f16)v1.x; av[5] = (f16)v1.y; av[6] = (f16)v1.z; av[7] = (f16)v1.w;
                } else {
                    av = *(const f16x8*)((const f16*)in + (size_t)arow * D_ + off);
                }
            }
            a[h] = av;
        }
#pragma unroll
        for (int ct = 0; ct < 8; ct++) {
            f16x8 b = *(const f16x8*)(Wt + (size_t)(ct * 16 + r) * D_ + off);
            acc[0][ct] = __builtin_amdgcn_mfma_f32_16x16x32_f16(a[0], b, acc[0][ct], 0, 0, 0);
            acc[1][ct] = __builtin_amdgcn_mfma_f32_16x16x32_f16(a[1], b, acc[1][ct], 0, 0, 0);
        }
    }
#pragma unroll
    for (int h = 0; h < 2; h++) {
#pragma unroll
        for (int ct = 0; ct < 8; ct++) {
            int c = ct * 16 + r;
            float bs = bias ? bias[c] : 0.0f;
#pragma unroll
            for (int j = 0; j < 4; j++) {
                int rr = row0 + h * 16 + kg * 4 + j;
                if (rr >= n) continue;
                float o = acc[h][ct][j] + bs;
                if (relu) o = fmaxf(o, 0.0f);
                outh[(size_t)rr * D_ + c] = (f16)o;
            }
        }
    }
}

// ======== fused GCN layer-1 + W2 GEMM: G2 = relu(agg(G1)*di + b1) @ W2 ========
// rows assigned via ord[] (degree/type-sorted -> uniform block gather time)
__global__ __launch_bounds__(256) void k_spmm1g(const f16* __restrict__ gsrc,
                                                const int* __restrict__ csr,
                                                const f16* __restrict__ w16,
                                                const int* __restrict__ rowstart,
                                                const float* __restrict__ dinv,
                                                const float* __restrict__ bias,
                                                const f16* __restrict__ Wt,
                                                const int* __restrict__ ord,
                                                f16* __restrict__ outG,
                                                int N, int rows) {
    __shared__ f16 hs[16][136];
    __shared__ int rid[16];
    int tid = (int)threadIdx.x;
    int lp = tid & 15;
    int row16 = tid >> 4;
    int gw = ord[blockIdx.x * 16 + row16];
    if (lp == 0) rid[row16] = gw;
    int t = (gw >= N) + (gw >= 2 * N);
    int tbase = t * N;
    int self = gw - tbase;                 // layer-1: shared N-row table
    int s0 = rowstart[gw], s1 = rowstart[gw + 1];
    float di = dinv[gw];
    size_t co = (size_t)(lp << 3);
    const f16* gp = gsrc + co;
    float a[8];
    {
        f16x8 sv = *(const f16x8*)(gp + (size_t)self * D_);
#pragma unroll
        for (int u = 0; u < 8; u++) a[u] = (float)sv[u] * di;
    }
    int j = s0;
    for (; j + 2 <= s1; j += 2) {
        int sA = csr[j], sB = csr[j + 1];
        float wA = (float)w16[j], wB = (float)w16[j + 1];
        f16x8 vA = *(const f16x8*)(gp + (size_t)sA * D_);
        f16x8 vB = *(const f16x8*)(gp + (size_t)sB * D_);
#pragma unroll
        for (int u = 0; u < 8; u++) a[u] = fmaf((float)vA[u], wA, a[u]);
#pragma unroll
        for (int u = 0; u < 8; u++) a[u] = fmaf((float)vB[u], wB, a[u]);
    }
    if (j < s1) {
        int s = csr[j];
        float w = (float)w16[j];
        f16x8 v = *(const f16x8*)(gp + (size_t)s * D_);
#pragma unroll
        for (int u = 0; u < 8; u++) a[u] = fmaf((float)v[u], w, a[u]);
    }
    float4 b0 = *(const float4*)(bias + co);
    float4 b1v = *(const float4*)(bias + co + 4);
    a[0] = fmaxf(fmaf(a[0], di, b0.x), 0.f);
    a[1] = fmaxf(fmaf(a[1], di, b0.y), 0.f);
    a[2] = fmaxf(fmaf(a[2], di, b0.z), 0.f);
    a[3] = fmaxf(fmaf(a[3], di, b0.w), 0.f);
    a[4] = fmaxf(fmaf(a[4], di, b1v.x), 0.f);
    a[5] = fmaxf(fmaf(a[5], di, b1v.y), 0.f);
    a[6] = fmaxf(fmaf(a[6], di, b1v.z), 0.f);
    a[7] = fmaxf(fmaf(a[7], di, b1v.w), 0.f);
    f16x8 hv;
#pragma unroll
    for (int u = 0; u < 8; u++) hv[u] = (f16)a[u];
    *(f16x8*)&hs[row16][lp << 3] = hv;
    __syncthreads();
    // phase 2: tile @ W2
    int l = tid & 63, wid = tid >> 6;
    int r = l & 15, kg = l >> 4;
    f16x8 af[4];
#pragma unroll
    for (int kk = 0; kk < 4; kk++) af[kk] = *(const f16x8*)&hs[r][kk * 32 + kg * 8];
#pragma unroll
    for (int ct = 0; ct < 2; ct++) {
        int c = wid * 32 + ct * 16 + r;
        f32x4 acc = {};
#pragma unroll
        for (int kk = 0; kk < 4; kk++) {
            f16x8 b = *(const f16x8*)(Wt + (size_t)c * D_ + kk * 32 + kg * 8);
            acc = __builtin_amdgcn_mfma_f32_16x16x32_f16(af[kk], b, acc, 0, 0, 0);
        }
#pragma unroll
        for (int j2 = 0; j2 < 4; j2++) {
            int grow = rid[kg * 4 + j2];
            outG[(size_t)grow * D_ + c] = (f16)acc[j2];
        }
    }
}

// ======== fused GCN layer-2 + semantic attention; z stored only for rows[:B] ========
__global__ __launch_bounds__(256) void k_spmm2a(const f16* __restrict__ gsrc,
                                                const int* __restrict__ csr,
                                                const f16* __restrict__ w16,
                                                const int* __restrict__ rowstart,
                                                const float* __restrict__ dinv,
                                                const float* __restrict__ bias,
                                                const f16* __restrict__ Wst,
                                                const float* __restrict__ bsem,
                                                const float* __restrict__ q,
                                                const int* __restrict__ ord,
                                                f16* __restrict__ Zb,
                                                float* __restrict__ att_part,
                                                int N, int rows, int B) {
    __shared__ f16 hs[16][136];
    __shared__ float ws[4];
    __shared__ int stype;
    int tid = (int)threadIdx.x;
    int lp = tid & 15;
    int row16 = tid >> 4;
    int gw = ord[blockIdx.x * 16 + row16];
    int t = (gw >= N) + (gw >= 2 * N);
    if (tid == 0) stype = t;
    int tbase = t * N;
    int self = gw;                          // layer-2: typed 3N-row table
    int s0 = rowstart[gw], s1 = rowstart[gw + 1];
    float di = dinv[gw];
    size_t co = (size_t)(lp << 3);
    const f16* gp = gsrc + co;
    float a[8];
    {
        f16x8 sv = *(const f16x8*)(gp + (size_t)self * D_);
#pragma unroll
        for (int u = 0; u < 8; u++) a[u] = (float)sv[u] * di;
    }
    int j = s0;
    for (; j + 2 <= s1; j += 2) {
        int sA = tbase + csr[j], sB = tbase + csr[j + 1];
        float wA = (float)w16[j], wB = (float)w16[j + 1];
        f16x8 vA = *(const f16x8*)(gp + (size_t)sA * D_);
        f16x8 vB = *(const f16x8*)(gp + (size_t)sB * D_);
#pragma unroll
        for (int u = 0; u < 8; u++) a[u] = fmaf((float)vA[u], wA, a[u]);
#pragma unroll
        for (int u = 0; u < 8; u++) a[u] = fmaf((float)vB[u], wB, a[u]);
    }
    if (j < s1) {
        int s = tbase + csr[j];
        float w = (float)w16[j];
        f16x8 v = *(const f16x8*)(gp + (size_t)s * D_);
#pragma unroll
        for (int u = 0; u < 8; u++) a[u] = fmaf((float)v[u], w, a[u]);
    }
    float4 b0 = *(const float4*)(bias + co);
    float4 b1v = *(const float4*)(bias + co + 4);
    a[0] = fmaxf(fmaf(a[0], di, b0.x), 0.f);
    a[1] = fmaxf(fmaf(a[1], di, b0.y), 0.f);
    a[2] = fmaxf(fmaf(a[2], di, b0.z), 0.f);
    a[3] = fmaxf(fmaf(a[3], di, b0.w), 0.f);
    a[4] = fmaxf(fmaf(a[4], di, b1v.x), 0.f);
    a[5] = fmaxf(fmaf(a[5], di, b1v.y), 0.f);
    a[6] = fmaxf(fmaf(a[6], di, b1v.z), 0.f);
    a[7] = fmaxf(fmaf(a[7], di, b1v.w), 0.f);
    f16x8 hv;
#pragma unroll
    for (int u = 0; u < 8; u++) hv[u] = (f16)a[u];
    *(f16x8*)&hs[row16][lp << 3] = hv;
    int local = gw - tbase;
    if (local < B) *(f16x8*)(Zb + ((size_t)t * B + local) * D_ + co) = hv;
    __syncthreads();
    // phase 2: attention scores for this 16-row tile
    int l = tid & 63, wid = tid >> 6;
    int r = l & 15, kg = l >> 4;
    f16x8 af[4];
#pragma unroll
    for (int kk = 0; kk < 4; kk++) af[kk] = *(const f16x8*)&hs[r][kk * 32 + kg * 8];
    float s = 0.0f;
#pragma unroll
    for (int ct = 0; ct < 2; ct++) {
        int c = wid * 32 + ct * 16 + r;
        f32x4 acc = {};
#pragma unroll
        for (int kk = 0; kk < 4; kk++) {
            f16x8 b = *(const f16x8*)(Wst + (size_t)c * D_ + kk * 32 + kg * 8);
            acc = __builtin_amdgcn_mfma_f32_16x16x32_f16(af[kk], b, acc, 0, 0, 0);
        }
        float qc = q[c], bc = bsem[c];
#pragma unroll
        for (int j2 = 0; j2 < 4; j2++) s += qc * tanhf(acc[j2] + bc);
    }
#pragma unroll
    for (int m = 1; m < 64; m <<= 1) s += __shfl_xor(s, m, 64);
    if (l == 0) ws[wid] = s;
    __syncthreads();
    if (tid == 0)
        atomicAdd(&att_part[((blockIdx.x & 63) << 2) + stype], ws[0] + ws[1] + ws[2] + ws[3]);
}

__global__ void k_attw(const float* __restrict__ att_part, float* __restrict__ att_w, float invN) {
    __shared__ float sb[3];
    int t = threadIdx.x;
    if (t < 3) {
        float s = 0.f;
        for (int i = 0; i < 64; i++) s += att_part[(i << 2) + t];
        sb[t] = s * invN;
    }
    __syncthreads();
    if (t == 0) {
        float m = fmaxf(sb[0], fmaxf(sb[1], sb[2]));
        float x0 = expf(sb[0] - m), x1 = expf(sb[1] - m), x2 = expf(sb[2] - m);
        float inv = 1.f / (x0 + x1 + x2);
        att_w[0] = x0 * inv; att_w[1] = x1 * inv; att_w[2] = x2 * inv;
    }
}

// ---------------- pos: column sums of combined rows (Zb fp16, [3][B][D]) ----------------
__global__ __launch_bounds__(256) void k_colsum(const f16* __restrict__ Z, size_t tstride,
                                                const float* __restrict__ att_w,
                                                float* __restrict__ colsum) {
    int c2 = threadIdx.x & 63;
    int rg = threadIdx.x >> 6;
    int nbase = blockIdx.x << 7;
    float w0 = att_w[0], w1 = att_w[1], w2 = att_w[2];
    float csx = 0.f, csy = 0.f;
    for (int i = rg; i < 128; i += 4) {
        size_t off = (size_t)(nbase + i) * D_ + (c2 << 1);
        h2v z0 = *(const h2v*)(Z + off);
        h2v z1 = *(const h2v*)(Z + tstride + off);
        h2v z2 = *(const h2v*)(Z + 2 * tstride + off);
        csx += w0 * (float)z0.x + w1 * (float)z1.x + w2 * (float)z2.x;
        csy += w0 * (float)z0.y + w1 * (float)z1.y + w2 * (float)z2.y;
    }
    __shared__ float red[4][128];
    red[rg][c2 << 1] = csx;
    red[rg][(c2 << 1) + 1] = csy;
    __syncthreads();
    if (rg == 0) {
        float sx = red[0][c2 << 1] + red[1][c2 << 1] + red[2][c2 << 1] + red[3][c2 << 1];
        float sy = red[0][(c2 << 1) + 1] + red[1][(c2 << 1) + 1] + red[2][(c2 << 1) + 1] + red[3][(c2 << 1) + 1];
        atomicAdd(&colsum[c2 << 1], sx);
        atomicAdd(&colsum[(c2 << 1) + 1], sy);
    }
}

__global__ void k_summary_c(const float* __restrict__ colsum, const float* __restrict__ sv,
                            const float* __restrict__ Wd, float* __restrict__ cvec,
                            float* __restrict__ out_summary) {
    __shared__ float sl[128];
    int t = threadIdx.x;
    float s = 0.5f * (sv[t] + colsum[t] * (1.0f / (float)BATCH_));
    sl[t] = s;
    out_summary[t] = s;
    __syncthreads();
    float a = 0.f;
    for (int j = 0; j < 128; j++) a = fmaf(Wd[t * D_ + j], sl[j], a);
    cvec[t] = a;
}

__global__ __launch_bounds__(256) void k_cscore(const f16* __restrict__ Z, size_t tstride,
                                                const float* __restrict__ att_w,
                                                const float* __restrict__ c,
                                                const float* __restrict__ bd,
                                                float* __restrict__ out, int B) {
    int gw = (int)((blockIdx.x * (long long)blockDim.x + threadIdx.x) >> 6);
    int lane = threadIdx.x & 63;
    if (gw >= B) return;
    size_t off = (size_t)gw * D_ + (lane << 1);
    float w0 = att_w[0], w1 = att_w[1], w2 = att_w[2];
    h2v z0 = *(const h2v*)(Z + off);
    h2v z1 = *(const h2v*)(Z + tstride + off);
    h2v z2 = *(const h2v*)(Z + 2 * tstride + off);
    float vx = w0 * (float)z0.x + w1 * (float)z1.x + w2 * (float)z2.x;
    float vy = w0 * (float)z0.y + w1 * (float)z1.y + w2 * (float)z2.y;
    float2 cc = *(const float2*)(c + (lane << 1));
    float a = vx * cc.x + vy * cc.y;
#pragma unroll
    for (int m = 1; m < 64; m <<= 1) a += __shfl_xor(a, m, 64);
    if (lane == 0) out[gw] = a + bd[0];
}

// ---------------- host launcher ----------------
extern "C" void kernel_launch(void* const* d_in, const int* in_sizes, int n_in,
                              void* d_out, int out_size, void* d_ws, size_t ws_size,
                              hipStream_t stream) {
    const float* x      = (const float*)d_in[0];
    const int*   ei     = (const int*)d_in[1];
    const int*   perm   = (const int*)d_in[2];
    const float* sv     = (const float*)d_in[3];
    const float* W_lin  = (const float*)d_in[5];
    const float* b_lin  = (const float*)d_in[6];
    const float* W1     = (const float*)d_in[7];
    const float* b1     = (const float*)d_in[8];
    const float* W2     = (const float*)d_in[9];
    const float* b2     = (const float*)d_in[10];
    const float* W_sem  = (const float*)d_in[11];
    const float* b_sem  = (const float*)d_in[12];
    const float* q_sem  = (const float*)d_in[13];
    const float* W_disc = (const float*)d_in[14];
    const float* b_disc = (const float*)d_in[15];
    float* out = (float*)d_out;

    int N = in_sizes[0] / D_;
    int E = in_sizes[1] / 6;
    int L = 3 * N;
    size_t ND = (size_t)N * D_;
    int B = BATCH_;
    size_t BD = (size_t)B * D_;
    int nbt = (N + (1 << BSH) - 1) >> BSH;
    int nbuk = 3 * nbt;

    char* ws = (char*)d_ws;
    size_t o = 0;
    auto alloc = [&](size_t bytes) -> char* {
        char* p = ws + o;
        o = (o + bytes + 255) & ~(size_t)255;
        return p;
    };
    float* dinv     = (float*)alloc((size_t)L * 4);
    int*   rowstart = (int*)alloc(((size_t)L + 1) * 4);
    int*   csr      = (int*)alloc(((size_t)3 * E + 16) * 4);
    int*   ord      = (int*)alloc((size_t)L * 4);
    int*   bcnt     = (int*)alloc(512 * 4);
    int*   bbase    = (int*)alloc(513 * 4);
    int*   bcur     = (int*)alloc(512 * 4);
    int*   dh       = (int*)alloc(768 * 4);
    int*   dcur     = (int*)alloc(768 * 4);
    float* att_part = (float*)alloc(256 * 4);
    float* att_w    = (float*)alloc(16 * 4);
    float* colsum   = (float*)alloc(128 * 4);
    float* cvec     = (float*)alloc(128 * 4);
    f16*   Wlt      = (f16*)alloc(128 * 128 * 2);
    f16*   W1t      = (f16*)alloc(128 * 128 * 2);
    f16*   W2t      = (f16*)alloc(128 * 128 * 2);
    f16*   Wst      = (f16*)alloc(128 * 128 * 2);
    f16*   Ah       = (f16*)alloc(ND * 2);        // relu(x@Wlin+b); reused later as w16
    f16*   G1h      = (f16*)alloc(ND * 2);
    f16*   G1p      = (f16*)alloc(ND * 2);
    f16*   G2all    = (f16*)alloc(3 * ND * 2);    // fused layer1+W2 output (3 types)
    f16*   Zb       = (f16*)alloc(3 * BD * 2);    // z[:B] per type; front reused as pairs
    size_t o_full = o;

    uint32_t* pairs = (uint32_t*)Zb;
    f16*      w16  = (f16*)Ah;

    if (o_full > ws_size || N >= (1 << 22) || (N & 15) || nbuk > 512 || B > N ||
        (size_t)3 * E * 4 > 3 * BD * 2 || (size_t)3 * E * 2 > ND * 2) {
        k_sentinel<<<256, 256, 0, stream>>>(out, out_size);
        return;
    }

    // weight transposes (f32 -> f16, [c][k])
    k_wt<<<64, 256, 0, stream>>>(W_lin, Wlt);
    k_wt<<<64, 256, 0, stream>>>(W1, W1t);
    k_wt<<<64, 256, 0, stream>>>(W2, W2t);
    k_wt<<<64, 256, 0, stream>>>(W_sem, Wst);

    // ---- bucketed CSR build ----
    long long tot = 3LL * E;
    k_zero32<<<2, 256, 0, stream>>>((uint32_t*)bcnt, 512);
    k_hist<<<2048, 256, 0, stream>>>(ei, bcnt, E, nbt, nbuk);
    k_bscan<<<1, 512, 0, stream>>>(bcnt, bbase, bcur, nbuk);
    int scat_grid = (int)((tot + TILE_ - 1) / TILE_);
    k_scatter<<<scat_grid, 256, 0, stream>>>(ei, bcur, pairs, E, nbt, nbuk);
    k_bucket<<<nbuk, 256, 0, stream>>>(pairs, bbase, rowstart, dinv, csr, N, nbt, nbuk, L);

    // ---- degree/type sort of rows ----
    k_zero32<<<2, 256, 0, stream>>>((uint32_t*)dh, 768);
    k_dhist<<<(L + 255) / 256, 256, 0, stream>>>(rowstart, dh, N, L);
    k_dscan<<<1, 1024, 0, stream>>>(dh, dcur, 768);
    k_dorder<<<(L + 255) / 256, 256, 0, stream>>>(rowstart, dcur, ord, N, L);

    int mgN_grid  = (N + 127) / 128;
    int spmm_grid = L / 16;
    int scoreB_grid = (B + 3) / 4;

    // shared: A = relu(x@Wlin+b);  G1 = A@W1;  G1p = G1[perm];  then Ah becomes w16
    k_mgemm<<<mgN_grid, 256, 0, stream>>>(x, 1, Wlt, b_lin, Ah, N, 1);
    k_mgemm<<<mgN_grid, 256, 0, stream>>>(Ah, 0, W1t, nullptr, G1h, N, 0);
    k_gath<<<(N * 64 + 255) / 256, 256, 0, stream>>>((const uint32_t*)G1h, perm,
                                                     (uint32_t*)G1p, N);
    k_wedge<<<2048, 256, 0, stream>>>(csr, dinv, w16, N, E);   // overwrites Ah (dead)

    for (int br = 0; br < 2; br++) {
        const f16* src1 = br ? G1p : G1h;
        float* aw = att_w + br * 8;
        k_zero32<<<1, 256, 0, stream>>>((uint32_t*)att_part, 256);
        // fused: G2 = relu(agg(G1)*di + b1) @ W2   (all 3 types, degree-sorted blocks)
        k_spmm1g<<<spmm_grid, 256, 0, stream>>>(src1, csr, w16, rowstart, dinv, b1,
                                                W2t, ord, G2all, N, L);
        // fused: z = relu(agg(G2)*di + b2) (stored [:B]); att_part += per-type scores
        k_spmm2a<<<spmm_grid, 256, 0, stream>>>(G2all, csr, w16, rowstart, dinv, b2,
                                                Wst, b_sem, q_sem, ord, Zb, att_part,
                                                N, L, B);
        k_attw<<<1, 64, 0, stream>>>(att_part, aw, 1.0f / (float)N);
        if (br == 0) {
            k_zero32<<<1, 256, 0, stream>>>((uint32_t*)colsum, 128);
            k_colsum<<<512, 256, 0, stream>>>(Zb, BD, aw, colsum);
            k_summary_c<<<1, 128, 0, stream>>>(colsum, sv, W_disc, cvec, out + 2 * (size_t)B);
            k_cscore<<<scoreB_grid, 256, 0, stream>>>(Zb, BD, aw, cvec, b_disc, out, B);
        } else {
            k_cscore<<<scoreB_grid, 256, 0, stream>>>(Zb, BD, aw, cvec, b_disc, out + B, B);
        }
    }
}

// Round 13
// 1208.373 us; speedup vs baseline: 1.6528x; 1.6528x over previous
//
#include <hip/hip_runtime.h>

#define D_ 128
#define BATCH_ 65536
#define BSH 10          // bucket = 1024 destinations
#define TILE_ 16384     // edges per scatter block
#define DTILE_ 2048     // rows per degree-sort block

typedef _Float16 f16;
typedef _Float16 h2v __attribute__((ext_vector_type(2)));
typedef _Float16 f16x8 __attribute__((ext_vector_type(8)));
typedef float f32x4 __attribute__((ext_vector_type(4)));

// ---------------- utility ----------------
__global__ void k_zero32(uint32_t* p, long long n) {
    long long i = (long long)blockIdx.x * blockDim.x + threadIdx.x;
    long long st = (long long)gridDim.x * blockDim.x;
    for (; i < n; i += st) p[i] = 0u;
}

__global__ void k_sentinel(float* p, long long n) {
    long long i = (long long)blockIdx.x * blockDim.x + threadIdx.x;
    long long st = (long long)gridDim.x * blockDim.x;
    for (; i < n; i += st) p[i] = -12345.0f;
}

// transpose+convert 128x128 weight: Wt[c][k] = (f16)W[k][c]
__global__ void k_wt(const float* __restrict__ W, f16* __restrict__ Wt) {
    int t = blockIdx.x * 256 + threadIdx.x;
    int k = t >> 7, c = t & 127;
    Wt[c * 128 + k] = (f16)W[k * 128 + c];
}

// row gather: dst[i][:] = src[perm[i]][:]   (fp16 rows as u32 pairs)
__global__ void k_gath(const uint32_t* __restrict__ src, const int* __restrict__ perm,
                       uint32_t* __restrict__ dst, int N) {
    int i = blockIdx.x * 256 + threadIdx.x;
    if (i >= N * 64) return;
    int row = i >> 6, col = i & 63;
    dst[i] = src[((size_t)perm[row] << 6) + col];
}

// ---------------- bucketed CSR build ----------------
__global__ void k_hist(const int* __restrict__ ei, int* __restrict__ bcnt,
                       int E, int nbt, int nbuk) {
    __shared__ int hist[512];
    for (int i = threadIdx.x; i < 512; i += 256) hist[i] = 0;
    __syncthreads();
    long long tot = 3LL * E;
    long long i = (long long)blockIdx.x * 256 + threadIdx.x;
    long long st = (long long)gridDim.x * 256;
    for (; i < tot; i += st) {
        int t = (i >= E) + (i >= 2LL * E);
        long long w = i - (long long)t * E;
        int dst = ei[(long long)t * 2 * E + E + w];
        atomicAdd(&hist[t * nbt + (dst >> BSH)], 1);
    }
    __syncthreads();
    for (int i2 = threadIdx.x; i2 < nbuk; i2 += 256)
        if (hist[i2]) atomicAdd(&bcnt[i2], hist[i2]);
}

__global__ void k_bscan(const int* __restrict__ bcnt, int* __restrict__ bbase,
                        int* __restrict__ bcur, int nbuk) {
    __shared__ int s[512];
    int t = threadIdx.x;
    int v = (t < nbuk) ? bcnt[t] : 0;
    s[t] = v;
    __syncthreads();
    for (int off = 1; off < 512; off <<= 1) {
        int a = (t >= off) ? s[t - off] : 0;
        __syncthreads();
        s[t] += a;
        __syncthreads();
    }
    if (t < nbuk) {
        int e = s[t] - v;
        bbase[t] = e;
        bcur[t] = e;
        if (t == nbuk - 1) bbase[nbuk] = s[t];
    }
}

__global__ __launch_bounds__(256) void k_scatter(const int* __restrict__ ei,
                                                 int* __restrict__ bcur,
                                                 uint32_t* __restrict__ pairs,
                                                 int E, int nbt, int nbuk) {
    __shared__ int hist[512];
    __shared__ int base[512];
    long long tot = 3LL * E;
    long long w0 = (long long)blockIdx.x * TILE_;
    long long w1 = w0 + TILE_ < tot ? w0 + TILE_ : tot;
    for (int i = threadIdx.x; i < 512; i += 256) hist[i] = 0;
    __syncthreads();
    for (long long e = w0 + threadIdx.x; e < w1; e += 256) {
        int t = (e >= E) + (e >= 2LL * E);
        long long w = e - (long long)t * E;
        int dst = ei[(long long)t * 2 * E + E + w];
        atomicAdd(&hist[t * nbt + (dst >> BSH)], 1);
    }
    __syncthreads();
    for (int i = threadIdx.x; i < nbuk; i += 256) {
        int c = hist[i];
        base[i] = c ? atomicAdd(&bcur[i], c) : 0;
        hist[i] = 0;
    }
    __syncthreads();
    for (long long e = w0 + threadIdx.x; e < w1; e += 256) {
        int t = (e >= E) + (e >= 2LL * E);
        long long w = e - (long long)t * E;
        int src = ei[(long long)t * 2 * E + w];
        int dst = ei[(long long)t * 2 * E + E + w];
        int b = t * nbt + (dst >> BSH);
        int off = atomicAdd(&hist[b], 1);
        pairs[base[b] + off] = (uint32_t)src | ((uint32_t)(dst & ((1 << BSH) - 1)) << 22);
    }
}

__global__ __launch_bounds__(256) void k_bucket(const uint32_t* __restrict__ pairs,
                                                const int* __restrict__ bbase,
                                                int* __restrict__ rowstart,
                                                float* __restrict__ dinv,
                                                int* __restrict__ csr,
                                                int N, int nbt, int nbuk, int L) {
    __shared__ int cnt[1024];
    __shared__ int pref[1024];
    __shared__ int sums[256];
    int b = blockIdx.x;
    int t = b / nbt, bb = b - t * nbt;
    int dst0 = bb << BSH;
    int ndst = (N - dst0 < 1024) ? (N - dst0) : 1024;
    int e0 = bbase[b], e1 = bbase[b + 1];
    int tid = threadIdx.x;
    for (int i = tid; i < 1024; i += 256) cnt[i] = 0;
    __syncthreads();
    for (int e = e0 + tid; e < e1; e += 256) atomicAdd(&cnt[pairs[e] >> 22], 1);
    __syncthreads();
    int i0 = tid * 4;
    int c0 = cnt[i0], c1 = cnt[i0 + 1], c2 = cnt[i0 + 2], c3 = cnt[i0 + 3];
    int s4 = c0 + c1 + c2 + c3;
    sums[tid] = s4;
    __syncthreads();
    for (int off = 1; off < 256; off <<= 1) {
        int v = (tid >= off) ? sums[tid - off] : 0;
        __syncthreads();
        sums[tid] += v;
        __syncthreads();
    }
    int run = sums[tid] - s4;
    pref[i0] = run; run += c0;
    pref[i0 + 1] = run; run += c1;
    pref[i0 + 2] = run; run += c2;
    pref[i0 + 3] = run;
    __syncthreads();
    for (int d = tid; d < ndst; d += 256) {
        int r = t * N + dst0 + d;
        rowstart[r] = e0 + pref[d];
        dinv[r] = rsqrtf((float)cnt[d] + 1.0f);
    }
    if (b == nbuk - 1 && tid == 0) rowstart[L] = e1;
    __syncthreads();
    for (int e = e0 + tid; e < e1; e += 256) {
        uint32_t u = pairs[e];
        int d = u >> 22;
        int pos = e0 + atomicAdd(&pref[d], 1);
        csr[pos] = (int)(u & ((1u << 22) - 1));
    }
}

// ---------------- degree sort (LDS-staged, scatter-style reservations) ----------------
__global__ __launch_bounds__(256) void k_dhist(const int* __restrict__ rowstart,
                                               int* __restrict__ dh, int N, int L) {
    __shared__ int hist[768];
    for (int i = threadIdx.x; i < 768; i += 256) hist[i] = 0;
    __syncthreads();
    int i = blockIdx.x * 256 + threadIdx.x;
    int st = gridDim.x * 256;
    for (int r = i; r < L; r += st) {
        int deg = rowstart[r + 1] - rowstart[r];
        if (deg > 255) deg = 255;
        int t = (r >= N) + (r >= 2 * N);
        atomicAdd(&hist[t * 256 + deg], 1);
    }
    __syncthreads();
    for (int k = threadIdx.x; k < 768; k += 256)
        if (hist[k]) atomicAdd(&dh[k], hist[k]);
}

__global__ void k_dscan(const int* __restrict__ dh, int* __restrict__ dcur, int nb) {
    __shared__ int s[1024];
    int t = threadIdx.x;
    int v = (t < nb) ? dh[t] : 0;
    s[t] = v;
    __syncthreads();
    for (int off = 1; off < 1024; off <<= 1) {
        int a = (t >= off) ? s[t - off] : 0;
        __syncthreads();
        s[t] += a;
        __syncthreads();
    }
    if (t < nb) dcur[t] = s[t] - v;
}

__global__ __launch_bounds__(256) void k_dorder(const int* __restrict__ rowstart,
                                                int* __restrict__ dcur,
                                                int* __restrict__ ord, int N, int L) {
    __shared__ int hist[768];
    __shared__ int base[768];
    int r0 = blockIdx.x * DTILE_;
    int r1 = r0 + DTILE_ < L ? r0 + DTILE_ : L;
    for (int i = threadIdx.x; i < 768; i += 256) hist[i] = 0;
    __syncthreads();
    for (int r = r0 + threadIdx.x; r < r1; r += 256) {
        int deg = rowstart[r + 1] - rowstart[r];
        if (deg > 255) deg = 255;
        int t = (r >= N) + (r >= 2 * N);
        atomicAdd(&hist[t * 256 + deg], 1);
    }
    __syncthreads();
    for (int k = threadIdx.x; k < 768; k += 256) {
        int c = hist[k];
        base[k] = c ? atomicAdd(&dcur[k], c) : 0;
        hist[k] = 0;
    }
    __syncthreads();
    for (int r = r0 + threadIdx.x; r < r1; r += 256) {
        int deg = rowstart[r + 1] - rowstart[r];
        if (deg > 255) deg = 255;
        int t = (r >= N) + (r >= 2 * N);
        int k = t * 256 + deg;
        int off = atomicAdd(&hist[k], 1);
        ord[base[k] + off] = r;
    }
}

// CSR-aligned edge weights: w16[e] = (f16)dinv_t[src_e]  (valid for BOTH layers)
__global__ void k_wedge(const int* __restrict__ csr, const float* __restrict__ dinv,
                        f16* __restrict__ w16, int N, int E) {
    long long tot = 3LL * E;
    long long i = (long long)blockIdx.x * 256 + threadIdx.x;
    long long st = (long long)gridDim.x * 256;
    for (; i < tot; i += st) {
        int t = (i >= E) + (i >= 2LL * E);
        w16[i] = (f16)dinv[t * N + csr[i]];
    }
}

// ---------------- MFMA GEMM: out(f16) = [relu](in @ W [+ bias]); 32 rows/wave ----------------
__global__ __launch_bounds__(256) void k_mgemm(const void* __restrict__ in, int in_f32,
                                               const f16* __restrict__ Wt,
                                               const float* __restrict__ bias,
                                               f16* __restrict__ outh, int n, int relu) {
    int l = threadIdx.x & 63, wid = threadIdx.x >> 6;
    int row0 = blockIdx.x * 128 + wid * 32;
    int r = l & 15, kg = l >> 4;
    f32x4 acc[2][8] = {};
#pragma unroll
    for (int kk = 0; kk < 4; kk++) {
        int off = kk * 32 + kg * 8;
        f16x8 a[2];
#pragma unroll
        for (int h = 0; h < 2; h++) {
            int arow = row0 + h * 16 + r;
            f16x8 av = {};
            if (arow < n) {
                if (in_f32) {
                    const float* inf = (const float*)in + (size_t)arow * D_ + off;
                    float4 v0 = *(const float4*)inf;
                    float4 v1 = *(const float4*)(inf + 4);
                    av[0] = (f16)v0.x; av[1] = (f16)v0.y; av[2] = (f16)v0.z; av[3] = (f16)v0.w;
                    av[4] = (f16)v1.x; av[5] = (f16)v1.y; av[6] = (f16)v1.z; av[7] = (f16)v1.w;
                } else {
                    av = *(const f16x8*)((const f16*)in + (size_t)arow * D_ + off);
                }
            }
            a[h] = av;
        }
#pragma unroll
        for (int ct = 0; ct < 8; ct++) {
            f16x8 b = *(const f16x8*)(Wt + (size_t)(ct * 16 + r) * D_ + off);
            acc[0][ct] = __builtin_amdgcn_mfma_f32_16x16x32_f16(a[0], b, acc[0][ct], 0, 0, 0);
            acc[1][ct] = __builtin_amdgcn_mfma_f32_16x16x32_f16(a[1], b, acc[1][ct], 0, 0, 0);
        }
    }
#pragma unroll
    for (int h = 0; h < 2; h++) {
#pragma unroll
        for (int ct = 0; ct < 8; ct++) {
            int c = ct * 16 + r;
            float bs = bias ? bias[c] : 0.0f;
#pragma unroll
            for (int j = 0; j < 4; j++) {
                int rr = row0 + h * 16 + kg * 4 + j;
                if (rr >= n) continue;
                float o = acc[h][ct][j] + bs;
                if (relu) o = fmaxf(o, 0.0f);
                outh[(size_t)rr * D_ + c] = (f16)o;
            }
        }
    }
}

// ======== fused GCN layer-1 + W2 GEMM: G2 = relu(agg(G1)*di + b1) @ W2 ========
// rows assigned via ord[] (degree/type-sorted -> uniform block gather time)
__global__ __launch_bounds__(256) void k_spmm1g(const f16* __restrict__ gsrc,
                                                const int* __restrict__ csr,
                                                const f16* __restrict__ w16,
                                                const int* __restrict__ rowstart,
                                                const float* __restrict__ dinv,
                                                const float* __restrict__ bias,
                                                const f16* __restrict__ Wt,
                                                const int* __restrict__ ord,
                                                f16* __restrict__ outG,
                                                int N, int rows) {
    __shared__ f16 hs[16][136];
    __shared__ int rid[16];
    int tid = (int)threadIdx.x;
    int lp = tid & 15;
    int row16 = tid >> 4;
    int gw = ord[blockIdx.x * 16 + row16];
    if (lp == 0) rid[row16] = gw;
    int t = (gw >= N) + (gw >= 2 * N);
    int tbase = t * N;
    int self = gw - tbase;                 // layer-1: shared N-row table
    int s0 = rowstart[gw], s1 = rowstart[gw + 1];
    float di = dinv[gw];
    size_t co = (size_t)(lp << 3);
    const f16* gp = gsrc + co;
    float a[8];
    {
        f16x8 sv = *(const f16x8*)(gp + (size_t)self * D_);
#pragma unroll
        for (int u = 0; u < 8; u++) a[u] = (float)sv[u] * di;
    }
    int j = s0;
    for (; j + 2 <= s1; j += 2) {
        int sA = csr[j], sB = csr[j + 1];
        float wA = (float)w16[j], wB = (float)w16[j + 1];
        f16x8 vA = *(const f16x8*)(gp + (size_t)sA * D_);
        f16x8 vB = *(const f16x8*)(gp + (size_t)sB * D_);
#pragma unroll
        for (int u = 0; u < 8; u++) a[u] = fmaf((float)vA[u], wA, a[u]);
#pragma unroll
        for (int u = 0; u < 8; u++) a[u] = fmaf((float)vB[u], wB, a[u]);
    }
    if (j < s1) {
        int s = csr[j];
        float w = (float)w16[j];
        f16x8 v = *(const f16x8*)(gp + (size_t)s * D_);
#pragma unroll
        for (int u = 0; u < 8; u++) a[u] = fmaf((float)v[u], w, a[u]);
    }
    float4 b0 = *(const float4*)(bias + co);
    float4 b1v = *(const float4*)(bias + co + 4);
    a[0] = fmaxf(fmaf(a[0], di, b0.x), 0.f);
    a[1] = fmaxf(fmaf(a[1], di, b0.y), 0.f);
    a[2] = fmaxf(fmaf(a[2], di, b0.z), 0.f);
    a[3] = fmaxf(fmaf(a[3], di, b0.w), 0.f);
    a[4] = fmaxf(fmaf(a[4], di, b1v.x), 0.f);
    a[5] = fmaxf(fmaf(a[5], di, b1v.y), 0.f);
    a[6] = fmaxf(fmaf(a[6], di, b1v.z), 0.f);
    a[7] = fmaxf(fmaf(a[7], di, b1v.w), 0.f);
    f16x8 hv;
#pragma unroll
    for (int u = 0; u < 8; u++) hv[u] = (f16)a[u];
    *(f16x8*)&hs[row16][lp << 3] = hv;
    __syncthreads();
    // phase 2: tile @ W2
    int l = tid & 63, wid = tid >> 6;
    int r = l & 15, kg = l >> 4;
    f16x8 af[4];
#pragma unroll
    for (int kk = 0; kk < 4; kk++) af[kk] = *(const f16x8*)&hs[r][kk * 32 + kg * 8];
#pragma unroll
    for (int ct = 0; ct < 2; ct++) {
        int c = wid * 32 + ct * 16 + r;
        f32x4 acc = {};
#pragma unroll
        for (int kk = 0; kk < 4; kk++) {
            f16x8 b = *(const f16x8*)(Wt + (size_t)c * D_ + kk * 32 + kg * 8);
            acc = __builtin_amdgcn_mfma_f32_16x16x32_f16(af[kk], b, acc, 0, 0, 0);
        }
#pragma unroll
        for (int j2 = 0; j2 < 4; j2++) {
            int grow = rid[kg * 4 + j2];
            outG[(size_t)grow * D_ + c] = (f16)acc[j2];
        }
    }
}

// ======== fused GCN layer-2 + semantic attention; z stored only for rows[:B] ========
__global__ __launch_bounds__(256) void k_spmm2a(const f16* __restrict__ gsrc,
                                                const int* __restrict__ csr,
                                                const f16* __restrict__ w16,
                                                const int* __restrict__ rowstart,
                                                const float* __restrict__ dinv,
                                                const float* __restrict__ bias,
                                                const f16* __restrict__ Wst,
                                                const float* __restrict__ bsem,
                                                const float* __restrict__ q,
                                                const int* __restrict__ ord,
                                                f16* __restrict__ Zb,
                                                float* __restrict__ att_part,
                                                int N, int rows, int B) {
    __shared__ f16 hs[16][136];
    __shared__ float ws[4];
    __shared__ int stype;
    int tid = (int)threadIdx.x;
    int lp = tid & 15;
    int row16 = tid >> 4;
    int gw = ord[blockIdx.x * 16 + row16];
    int t = (gw >= N) + (gw >= 2 * N);
    if (tid == 0) stype = t;
    int tbase = t * N;
    int self = gw;                          // layer-2: typed 3N-row table
    int s0 = rowstart[gw], s1 = rowstart[gw + 1];
    float di = dinv[gw];
    size_t co = (size_t)(lp << 3);
    const f16* gp = gsrc + co;
    float a[8];
    {
        f16x8 sv = *(const f16x8*)(gp + (size_t)self * D_);
#pragma unroll
        for (int u = 0; u < 8; u++) a[u] = (float)sv[u] * di;
    }
    int j = s0;
    for (; j + 2 <= s1; j += 2) {
        int sA = tbase + csr[j], sB = tbase + csr[j + 1];
        float wA = (float)w16[j], wB = (float)w16[j + 1];
        f16x8 vA = *(const f16x8*)(gp + (size_t)sA * D_);
        f16x8 vB = *(const f16x8*)(gp + (size_t)sB * D_);
#pragma unroll
        for (int u = 0; u < 8; u++) a[u] = fmaf((float)vA[u], wA, a[u]);
#pragma unroll
        for (int u = 0; u < 8; u++) a[u] = fmaf((float)vB[u], wB, a[u]);
    }
    if (j < s1) {
        int s = tbase + csr[j];
        float w = (float)w16[j];
        f16x8 v = *(const f16x8*)(gp + (size_t)s * D_);
#pragma unroll
        for (int u = 0; u < 8; u++) a[u] = fmaf((float)v[u], w, a[u]);
    }
    float4 b0 = *(const float4*)(bias + co);
    float4 b1v = *(const float4*)(bias + co + 4);
    a[0] = fmaxf(fmaf(a[0], di, b0.x), 0.f);
    a[1] = fmaxf(fmaf(a[1], di, b0.y), 0.f);
    a[2] = fmaxf(fmaf(a[2], di, b0.z), 0.f);
    a[3] = fmaxf(fmaf(a[3], di, b0.w), 0.f);
    a[4] = fmaxf(fmaf(a[4], di, b1v.x), 0.f);
    a[5] = fmaxf(fmaf(a[5], di, b1v.y), 0.f);
    a[6] = fmaxf(fmaf(a[6], di, b1v.z), 0.f);
    a[7] = fmaxf(fmaf(a[7], di, b1v.w), 0.f);
    f16x8 hv;
#pragma unroll
    for (int u = 0; u < 8; u++) hv[u] = (f16)a[u];
    *(f16x8*)&hs[row16][lp << 3] = hv;
    int local = gw - tbase;
    if (local < B) *(f16x8*)(Zb + ((size_t)t * B + local) * D_ + co) = hv;
    __syncthreads();
    // phase 2: attention scores for this 16-row tile
    int l = tid & 63, wid = tid >> 6;
    int r = l & 15, kg = l >> 4;
    f16x8 af[4];
#pragma unroll
    for (int kk = 0; kk < 4; kk++) af[kk] = *(const f16x8*)&hs[r][kk * 32 + kg * 8];
    float s = 0.0f;
#pragma unroll
    for (int ct = 0; ct < 2; ct++) {
        int c = wid * 32 + ct * 16 + r;
        f32x4 acc = {};
#pragma unroll
        for (int kk = 0; kk < 4; kk++) {
            f16x8 b = *(const f16x8*)(Wst + (size_t)c * D_ + kk * 32 + kg * 8);
            acc = __builtin_amdgcn_mfma_f32_16x16x32_f16(af[kk], b, acc, 0, 0, 0);
        }
        float qc = q[c], bc = bsem[c];
#pragma unroll
        for (int j2 = 0; j2 < 4; j2++) s += qc * tanhf(acc[j2] + bc);
    }
#pragma unroll
    for (int m = 1; m < 64; m <<= 1) s += __shfl_xor(s, m, 64);
    if (l == 0) ws[wid] = s;
    __syncthreads();
    if (tid == 0)
        atomicAdd(&att_part[((blockIdx.x & 63) << 2) + stype], ws[0] + ws[1] + ws[2] + ws[3]);
}

__global__ void k_attw(const float* __restrict__ att_part, float* __restrict__ att_w, float invN) {
    __shared__ float sb[3];
    int t = threadIdx.x;
    if (t < 3) {
        float s = 0.f;
        for (int i = 0; i < 64; i++) s += att_part[(i << 2) + t];
        sb[t] = s * invN;
    }
    __syncthreads();
    if (t == 0) {
        float m = fmaxf(sb[0], fmaxf(sb[1], sb[2]));
        float x0 = expf(sb[0] - m), x1 = expf(sb[1] - m), x2 = expf(sb[2] - m);
        float inv = 1.f / (x0 + x1 + x2);
        att_w[0] = x0 * inv; att_w[1] = x1 * inv; att_w[2] = x2 * inv;
    }
}

// ---------------- pos: column sums of combined rows (Zb fp16, [3][B][D]) ----------------
__global__ __launch_bounds__(256) void k_colsum(const f16* __restrict__ Z, size_t tstride,
                                                const float* __restrict__ att_w,
                                                float* __restrict__ colsum) {
    int c2 = threadIdx.x & 63;
    int rg = threadIdx.x >> 6;
    int nbase = blockIdx.x << 7;
    float w0 = att_w[0], w1 = att_w[1], w2 = att_w[2];
    float csx = 0.f, csy = 0.f;
    for (int i = rg; i < 128; i += 4) {
        size_t off = (size_t)(nbase + i) * D_ + (c2 << 1);
        h2v z0 = *(const h2v*)(Z + off);
        h2v z1 = *(const h2v*)(Z + tstride + off);
        h2v z2 = *(const h2v*)(Z + 2 * tstride + off);
        csx += w0 * (float)z0.x + w1 * (float)z1.x + w2 * (float)z2.x;
        csy += w0 * (float)z0.y + w1 * (float)z1.y + w2 * (float)z2.y;
    }
    __shared__ float red[4][128];
    red[rg][c2 << 1] = csx;
    red[rg][(c2 << 1) + 1] = csy;
    __syncthreads();
    if (rg == 0) {
        float sx = red[0][c2 << 1] + red[1][c2 << 1] + red[2][c2 << 1] + red[3][c2 << 1];
        float sy = red[0][(c2 << 1) + 1] + red[1][(c2 << 1) + 1] + red[2][(c2 << 1) + 1] + red[3][(c2 << 1) + 1];
        atomicAdd(&colsum[c2 << 1], sx);
        atomicAdd(&colsum[(c2 << 1) + 1], sy);
    }
}

__global__ void k_summary_c(const float* __restrict__ colsum, const float* __restrict__ sv,
                            const float* __restrict__ Wd, float* __restrict__ cvec,
                            float* __restrict__ out_summary) {
    __shared__ float sl[128];
    int t = threadIdx.x;
    float s = 0.5f * (sv[t] + colsum[t] * (1.0f / (float)BATCH_));
    sl[t] = s;
    out_summary[t] = s;
    __syncthreads();
    float a = 0.f;
    for (int j = 0; j < 128; j++) a = fmaf(Wd[t * D_ + j], sl[j], a);
    cvec[t] = a;
}

__global__ __launch_bounds__(256) void k_cscore(const f16* __restrict__ Z, size_t tstride,
                                                const float* __restrict__ att_w,
                                                const float* __restrict__ c,
                                                const float* __restrict__ bd,
                                                float* __restrict__ out, int B) {
    int gw = (int)((blockIdx.x * (long long)blockDim.x + threadIdx.x) >> 6);
    int lane = threadIdx.x & 63;
    if (gw >= B) return;
    size_t off = (size_t)gw * D_ + (lane << 1);
    float w0 = att_w[0], w1 = att_w[1], w2 = att_w[2];
    h2v z0 = *(const h2v*)(Z + off);
    h2v z1 = *(const h2v*)(Z + tstride + off);
    h2v z2 = *(const h2v*)(Z + 2 * tstride + off);
    float vx = w0 * (float)z0.x + w1 * (float)z1.x + w2 * (float)z2.x;
    float vy = w0 * (float)z0.y + w1 * (float)z1.y + w2 * (float)z2.y;
    float2 cc = *(const float2*)(c + (lane << 1));
    float a = vx * cc.x + vy * cc.y;
#pragma unroll
    for (int m = 1; m < 64; m <<= 1) a += __shfl_xor(a, m, 64);
    if (lane == 0) out[gw] = a + bd[0];
}

// ---------------- host launcher ----------------
extern "C" void kernel_launch(void* const* d_in, const int* in_sizes, int n_in,
                              void* d_out, int out_size, void* d_ws, size_t ws_size,
                              hipStream_t stream) {
    const float* x      = (const float*)d_in[0];
    const int*   ei     = (const int*)d_in[1];
    const int*   perm   = (const int*)d_in[2];
    const float* sv     = (const float*)d_in[3];
    const float* W_lin  = (const float*)d_in[5];
    const float* b_lin  = (const float*)d_in[6];
    const float* W1     = (const float*)d_in[7];
    const float* b1     = (const float*)d_in[8];
    const float* W2     = (const float*)d_in[9];
    const float* b2     = (const float*)d_in[10];
    const float* W_sem  = (const float*)d_in[11];
    const float* b_sem  = (const float*)d_in[12];
    const float* q_sem  = (const float*)d_in[13];
    const float* W_disc = (const float*)d_in[14];
    const float* b_disc = (const float*)d_in[15];
    float* out = (float*)d_out;

    int N = in_sizes[0] / D_;
    int E = in_sizes[1] / 6;
    int L = 3 * N;
    size_t ND = (size_t)N * D_;
    int B = BATCH_;
    size_t BD = (size_t)B * D_;
    int nbt = (N + (1 << BSH) - 1) >> BSH;
    int nbuk = 3 * nbt;

    char* ws = (char*)d_ws;
    size_t o = 0;
    auto alloc = [&](size_t bytes) -> char* {
        char* p = ws + o;
        o = (o + bytes + 255) & ~(size_t)255;
        return p;
    };
    float* dinv     = (float*)alloc((size_t)L * 4);
    int*   rowstart = (int*)alloc(((size_t)L + 1) * 4);
    int*   csr      = (int*)alloc(((size_t)3 * E + 16) * 4);
    int*   ord      = (int*)alloc((size_t)L * 4);
    int*   bcnt     = (int*)alloc(512 * 4);
    int*   bbase    = (int*)alloc(513 * 4);
    int*   bcur     = (int*)alloc(512 * 4);
    int*   dh       = (int*)alloc(768 * 4);
    int*   dcur     = (int*)alloc(768 * 4);
    float* att_part = (float*)alloc(256 * 4);
    float* att_w    = (float*)alloc(16 * 4);
    float* colsum   = (float*)alloc(128 * 4);
    float* cvec     = (float*)alloc(128 * 4);
    f16*   Wlt      = (f16*)alloc(128 * 128 * 2);
    f16*   W1t      = (f16*)alloc(128 * 128 * 2);
    f16*   W2t      = (f16*)alloc(128 * 128 * 2);
    f16*   Wst      = (f16*)alloc(128 * 128 * 2);
    f16*   Ah       = (f16*)alloc(ND * 2);        // relu(x@Wlin+b); reused later as w16
    f16*   G1h      = (f16*)alloc(ND * 2);
    f16*   G1p      = (f16*)alloc(ND * 2);
    f16*   G2all    = (f16*)alloc(3 * ND * 2);    // fused layer1+W2 output (3 types)
    f16*   Zb       = (f16*)alloc(3 * BD * 2);    // z[:B] per type; front reused as pairs
    size_t o_full = o;

    uint32_t* pairs = (uint32_t*)Zb;
    f16*      w16  = (f16*)Ah;

    if (o_full > ws_size || N >= (1 << 22) || (N & 15) || nbuk > 512 || B > N ||
        (size_t)3 * E * 4 > 3 * BD * 2 || (size_t)3 * E * 2 > ND * 2) {
        k_sentinel<<<256, 256, 0, stream>>>(out, out_size);
        return;
    }

    // weight transposes (f32 -> f16, [c][k])
    k_wt<<<64, 256, 0, stream>>>(W_lin, Wlt);
    k_wt<<<64, 256, 0, stream>>>(W1, W1t);
    k_wt<<<64, 256, 0, stream>>>(W2, W2t);
    k_wt<<<64, 256, 0, stream>>>(W_sem, Wst);

    // ---- bucketed CSR build ----
    long long tot = 3LL * E;
    k_zero32<<<2, 256, 0, stream>>>((uint32_t*)bcnt, 512);
    k_hist<<<2048, 256, 0, stream>>>(ei, bcnt, E, nbt, nbuk);
    k_bscan<<<1, 512, 0, stream>>>(bcnt, bbase, bcur, nbuk);
    int scat_grid = (int)((tot + TILE_ - 1) / TILE_);
    k_scatter<<<scat_grid, 256, 0, stream>>>(ei, bcur, pairs, E, nbt, nbuk);
    k_bucket<<<nbuk, 256, 0, stream>>>(pairs, bbase, rowstart, dinv, csr, N, nbt, nbuk, L);

    // ---- degree/type sort of rows (LDS-staged) ----
    k_zero32<<<2, 256, 0, stream>>>((uint32_t*)dh, 768);
    k_dhist<<<256, 256, 0, stream>>>(rowstart, dh, N, L);
    k_dscan<<<1, 1024, 0, stream>>>(dh, dcur, 768);
    k_dorder<<<(L + DTILE_ - 1) / DTILE_, 256, 0, stream>>>(rowstart, dcur, ord, N, L);

    int mgN_grid  = (N + 127) / 128;
    int spmm_grid = L / 16;
    int scoreB_grid = (B + 3) / 4;

    // shared: A = relu(x@Wlin+b);  G1 = A@W1;  G1p = G1[perm];  then Ah becomes w16
    k_mgemm<<<mgN_grid, 256, 0, stream>>>(x, 1, Wlt, b_lin, Ah, N, 1);
    k_mgemm<<<mgN_grid, 256, 0, stream>>>(Ah, 0, W1t, nullptr, G1h, N, 0);
    k_gath<<<(N * 64 + 255) / 256, 256, 0, stream>>>((const uint32_t*)G1h, perm,
                                                     (uint32_t*)G1p, N);
    k_wedge<<<2048, 256, 0, stream>>>(csr, dinv, w16, N, E);   // overwrites Ah (dead)

    for (int br = 0; br < 2; br++) {
        const f16* src1 = br ? G1p : G1h;
        float* aw = att_w + br * 8;
        k_zero32<<<1, 256, 0, stream>>>((uint32_t*)att_part, 256);
        // fused: G2 = relu(agg(G1)*di + b1) @ W2   (all 3 types, degree-sorted blocks)
        k_spmm1g<<<spmm_grid, 256, 0, stream>>>(src1, csr, w16, rowstart, dinv, b1,
                                                W2t, ord, G2all, N, L);
        // fused: z = relu(agg(G2)*di + b2) (stored [:B]); att_part += per-type scores
        k_spmm2a<<<spmm_grid, 256, 0, stream>>>(G2all, csr, w16, rowstart, dinv, b2,
                                                Wst, b_sem, q_sem, ord, Zb, att_part,
                                                N, L, B);
        k_attw<<<1, 64, 0, stream>>>(att_part, aw, 1.0f / (float)N);
        if (br == 0) {
            k_zero32<<<1, 256, 0, stream>>>((uint32_t*)colsum, 128);
            k_colsum<<<512, 256, 0, stream>>>(Zb, BD, aw, colsum);
            k_summary_c<<<1, 128, 0, stream>>>(colsum, sv, W_disc, cvec, out + 2 * (size_t)B);
            k_cscore<<<scoreB_grid, 256, 0, stream>>>(Zb, BD, aw, cvec, b_disc, out, B);
        } else {
            k_cscore<<<scoreB_grid, 256, 0, stream>>>(Zb, BD, aw, cvec, b_disc, out + B, B);
        }
    }
}